// Round 13
// baseline (10551.416 us; speedup 1.0000x reference)
//
#include <hip/hip_runtime.h>
#include <hip/hip_bf16.h>

#define B_ 32
#define T_ 2048
#define D_ 512
#define H_ 1024
#define G4_ 4096
#define NBLK 128   // 2 batch-groups x 64 col-groups; 1 block/CU, co-resident
#define CG_ 64     // col groups
#define JPB 16     // h-columns per col-group (H_/CG_)
#define MROW 16    // batch rows per batch-group

typedef __attribute__((ext_vector_type(8))) short short8;
typedef __attribute__((ext_vector_type(4))) float f32x4;
typedef __attribute__((ext_vector_type(4))) int i32x4;

__device__ __forceinline__ float sigmoidf_(float x) { return 1.0f / (1.0f + __expf(-x)); }
__device__ __forceinline__ float tanhf_(float x) {
  float e = __expf(2.0f * x);
  return 1.0f - 2.0f / (e + 1.0f);
}
__device__ __forceinline__ unsigned short f_to_bf16bits(float f) {
  __hip_bfloat16 h = __float2bfloat16(f);
  return __builtin_bit_cast(unsigned short, h);
}

// 16B load bypassing L1/L2 (sc0 sc1): fresh from memory-side LLC, coalesces.
__device__ __forceinline__ i32x4 load16_sys(const void* p) {
  i32x4 v;
  asm volatile("global_load_dwordx4 %0, %1, off sc0 sc1" : "=v"(v) : "v"(p));
  return v;
}
// 4B LLC-fresh load (sc0 sc1), value ready on return (vmcnt inside). Coalesces.
__device__ __forceinline__ int load4_sys(const int* p) {
  int v;
  asm volatile("global_load_dword %0, %1, off sc0 sc1\n\t"
               "s_waitcnt vmcnt(0)"
               : "=v"(v) : "v"(p) : "memory");
  return v;
}
// 16B store written through to LLC (sc0 sc1); drained by explicit vmcnt(0).
__device__ __forceinline__ void store16_sys(void* p, i32x4 v) {
  asm volatile("global_store_dwordx4 %0, %1, off sc0 sc1" :: "v"(p), "v"(v) : "memory");
}

// ---------------------------------------------------------------------------
// Precompute xg[row][col] = sum_k x[row][k] * W_ih[col][k]   (row = tloc*32+b)
// ---------------------------------------------------------------------------
__global__ __launch_bounds__(256) void xw_gemm(const float* __restrict__ x,
                                               const float* __restrict__ Wih,
                                               __hip_bfloat16* __restrict__ xg,
                                               int t0) {
  __shared__ __align__(16) __hip_bfloat16 As[128][40];
  __shared__ __align__(16) __hip_bfloat16 Bs[128][40];
  __shared__ __align__(16) __hip_bfloat16 Cs[128][132];

  const int tid = threadIdx.x;
  const int bx = blockIdx.x;           // N tile (0..31)
  const int by = blockIdx.y;           // M tile
  const int lane = tid & 63, wave = tid >> 6;
  const int wm = wave >> 1, wn = wave & 1;
  const int lr = lane & 15, kq = (lane >> 4) * 8;

  const int r  = tid >> 1, ks = (tid & 1) * 16;
  const int rowA = by * 128 + r;
  const int bb = rowA & 31, tg = t0 + (rowA >> 5);
  const float* aptr = x  + ((size_t)bb * T_ + tg) * D_ + ks;
  const float* bptr = Wih + (size_t)(bx * 128 + r) * D_ + ks;

  f32x4 acc[4][4];
#pragma unroll
  for (int i = 0; i < 4; ++i)
#pragma unroll
    for (int jj = 0; jj < 4; ++jj) acc[i][jj] = (f32x4){0.f, 0.f, 0.f, 0.f};

  for (int k0 = 0; k0 < D_; k0 += 32) {
    __hip_bfloat16 ta[16], tb[16];
#pragma unroll
    for (int q = 0; q < 4; ++q) {
      f32x4 va = ((const f32x4*)(aptr + k0))[q];
      f32x4 vb = ((const f32x4*)(bptr + k0))[q];
#pragma unroll
      for (int e = 0; e < 4; ++e) {
        ta[q * 4 + e] = __float2bfloat16(va[e]);
        tb[q * 4 + e] = __float2bfloat16(vb[e]);
      }
    }
    __syncthreads();  // protect previous iter's readers
    *(short8*)&As[r][ks]     = *(const short8*)&ta[0];
    *(short8*)&As[r][ks + 8] = *(const short8*)&ta[8];
    *(short8*)&Bs[r][ks]     = *(const short8*)&tb[0];
    *(short8*)&Bs[r][ks + 8] = *(const short8*)&tb[8];
    __syncthreads();

    short8 af[4], bf[4];
#pragma unroll
    for (int mi = 0; mi < 4; ++mi) af[mi] = *(const short8*)&As[wm * 64 + mi * 16 + lr][kq];
#pragma unroll
    for (int ni = 0; ni < 4; ++ni) bf[ni] = *(const short8*)&Bs[wn * 64 + ni * 16 + lr][kq];
#pragma unroll
    for (int mi = 0; mi < 4; ++mi)
#pragma unroll
      for (int ni = 0; ni < 4; ++ni)
        acc[mi][ni] = __builtin_amdgcn_mfma_f32_16x16x32_bf16(af[mi], bf[ni], acc[mi][ni], 0, 0, 0);
  }

#pragma unroll
  for (int mi = 0; mi < 4; ++mi)
#pragma unroll
    for (int ni = 0; ni < 4; ++ni)
#pragma unroll
      for (int rr = 0; rr < 4; ++rr)
        Cs[wm * 64 + mi * 16 + (lane >> 4) * 4 + rr][wn * 64 + ni * 16 + lr] =
            __float2bfloat16(acc[mi][ni][rr]);
  __syncthreads();

  const int orow = tid >> 1, oseg = (tid & 1) * 64;
  __hip_bfloat16* dst = xg + (size_t)(by * 128 + orow) * G4_ + bx * 128 + oseg;
#pragma unroll
  for (int c2 = 0; c2 < 8; ++c2)
    *(short8*)(dst + c2 * 8) = *(const short8*)&Cs[orow][oseg + c2 * 8];
}

// ---------------------------------------------------------------------------
// Persistent recurrent kernel: 128 blocks x 256 thr (4 waves), batch-split
// (R9/R12 data path). Restructured step: ONE barrier + PER-WAVE flags.
//  - Gs double-buffered by step parity -> no end-of-step barrier needed.
//    (A wave writing Gs[t&1] at step t has passed barrier(t-1); any sibling
//    wave only reaches barrier(t-1) after its step-(t-2) read of Gs[t&1].)
//  - flag[bg][cg][pw] posted by wave pw right after ITS h-store vmcnt drain.
//    Any flag = t+1 implies that block passed its step-t barrier (flag comes
//    after it), hence ALL its step-t h reads of hbuf[t&1] are done -> same
//    overwrite-hazard certificate as R9's block-level flag, posted earlier.
//  - Consumer wave w polls its 64 flags (producers cgp in [16w,16w+16) x 4
//    waves, contiguous) with one coalesced load; the 4 waves' poll ranges
//    union to all 256 flags and join at the single barrier before any store.
// Deadlock-free: flags monotone; self-flag satisfied sequentially; lockstep
// window +-1 step as before. Chunk boundaries: loop skips when t0 >= tend.
// ---------------------------------------------------------------------------
__global__ __launch_bounds__(256, 1) void lstm_rec(
    const __hip_bfloat16* __restrict__ xg, const float* __restrict__ Whh,
    const int* __restrict__ lengths, const float* __restrict__ h0,
    const float* __restrict__ c0, const float* __restrict__ bih,
    const float* __restrict__ bhh, __hip_bfloat16* hbuf,
    float* __restrict__ hstate, float* __restrict__ cstate,
    int* flags, float* __restrict__ out,
    int t0, int t1, int isfirst, int islast) {
  __shared__ float Gs[2][4][MROW][68];   // [parity][k-slice][batch row][gate col]

  const int bid = blockIdx.x, tid = threadIdx.x;
  const int bg = bid & 1, cg = bid >> 1;
  const int lane = tid & 63, w = tid >> 6;
  const int lr = lane & 15, q = lane >> 4, kq = q * 8;
  const int kkb = w * 8;                 // kk range [kkb,kkb+8), k = kk*32+kq+e

  // --- W_hh fragments -> registers (stationary). wf[ni][kk2]:
  // gate ni, h-col cg*16+lr; k = (kkb+kk2)*32 + kq + e
  short8 wf[4][8];
#pragma unroll
  for (int ni = 0; ni < 4; ++ni) {
    const int gcol = ni * H_ + cg * JPB + lr;
    const float* wbase = Whh + (size_t)gcol * H_ + kq;
#pragma unroll
    for (int kk2 = 0; kk2 < 8; ++kk2) {
      const int k0 = (kkb + kk2) * 32;
      f32x4 w0 = *(const f32x4*)(wbase + k0);
      f32x4 w1 = *(const f32x4*)(wbase + k0 + 4);
      __hip_bfloat16 tw_[8];
#pragma unroll
      for (int e = 0; e < 4; ++e) { tw_[e] = __float2bfloat16(w0[e]); tw_[4 + e] = __float2bfloat16(w1[e]); }
      wf[ni][kk2] = *(const short8*)&tw_[0];
    }
  }

  // nonlinearity ownership: ALL 256 threads, each owns (batch row bloc, col j1)
  const int bloc = tid >> 4, j1 = tid & 15;
  const int b = bg * MROW + bloc;
  const int jglob = cg * JPB + j1;
  const int len_b = lengths[b];
  int maxlen = 0;
  for (int p = 0; p < B_; ++p) maxlen = max(maxlen, lengths[p]);
  const int tend = min(t1, maxlen);

  float hreg, creg, bias[4];
  if (isfirst) { hreg = h0[b * H_ + jglob]; creg = c0[b * H_ + jglob]; }
  else         { hreg = hstate[b * H_ + jglob]; creg = cstate[b * H_ + jglob]; }
#pragma unroll
  for (int p = 0; p < 4; ++p) bias[p] = bih[p * H_ + jglob] + bhh[p * H_ + jglob];

  // wave w polls flags of producers (bg, cgp in [16w,16w+16)) x waves 0..3:
  // index bg*256 + cgp*4 + pw -> contiguous 64 ints at bg*256 + w*64.
  const int* myflag = &flags[bg * 256 + w * 64 + lane];
  const int myflag_post = bg * 256 + cg * 4 + w;   // this wave's own flag
  // producer store: lanes tid%8==0 store 16B; 2 stores per batch row
  char* const hstore_base = (char*)hbuf;
  const size_t poff = (size_t)b * (H_ * 2) + cg * (JPB * 2) + ((tid >> 3) & 1) * 16;

  for (int t = t0; t < tend; ++t) {
    // ---- xg loads: independent of h -> issue before the poll ----
    float xv[4];
    {
      const __hip_bfloat16* xgrow = xg + ((size_t)(t - t0) * B_ + b) * G4_ + jglob;
#pragma unroll
      for (int p = 0; p < 4; ++p) xv[p] = __bfloat162float(xgrow[p * H_]);
    }

    // ---- per-wave poll: one coalesced read of this wave's 64 producer flags
    while (true) {
      int f = load4_sys(myflag);
      if (__all(f >= t)) break;
      __builtin_amdgcn_s_sleep(1);
    }

    // ---- A-fragments: coalescing 16B L2-bypass loads (16 rows only) ----
    const char* hb = (const char*)(hbuf + (size_t)(t & 1) * (B_ * H_));
    const char* rowp = hb + (size_t)(bg * MROW + lr) * (H_ * 2) + kkb * 64 + q * 16;
    i32x4 raw[8];
#pragma unroll
    for (int kk2 = 0; kk2 < 8; ++kk2)
      raw[kk2] = load16_sys(rowp + kk2 * 64);
    asm volatile("s_waitcnt vmcnt(0)" ::: "memory");
    __builtin_amdgcn_sched_barrier(0);

    short8 af[8];
#pragma unroll
    for (int kk2 = 0; kk2 < 8; ++kk2) {
      union { i32x4 i; short8 s; } cv;
      cv.i = raw[kk2];
      af[kk2] = cv.s;
    }

    // ---- MFMA: 16x64 tile over this wave's K=256 slice ----
    f32x4 acc[4];
#pragma unroll
    for (int ni = 0; ni < 4; ++ni) acc[ni] = (f32x4){0.f, 0.f, 0.f, 0.f};
#pragma unroll
    for (int kk2 = 0; kk2 < 8; ++kk2)
#pragma unroll
      for (int ni = 0; ni < 4; ++ni)
        acc[ni] = __builtin_amdgcn_mfma_f32_16x16x32_bf16(af[kk2], wf[ni][kk2], acc[ni], 0, 0, 0);

    // ---- write partials to this parity's Gs ----
#pragma unroll
    for (int ni = 0; ni < 4; ++ni)
#pragma unroll
      for (int rr = 0; rr < 4; ++rr)
        Gs[t & 1][w][q * 4 + rr][ni * 16 + lr] = acc[ni][rr];
    __syncthreads();   // the ONLY barrier: joins all waves' step-t reads+MFMA

    // ---- nonlinearity + per-wave h store + per-wave flag ----
    {
      const int upd = (t < len_b);
      const float (*G)[MROW][68] = Gs[t & 1];
      float s[4];
#pragma unroll
      for (int p = 0; p < 4; ++p) {
        const int cb = p * 16 + j1;
        s[p] = (G[0][bloc][cb] + G[1][bloc][cb]) + (G[2][bloc][cb] + G[3][bloc][cb]);
      }
      const float ig = sigmoidf_(s[0] + xv[0] + bias[0]);
      const float fg = sigmoidf_(s[1] + xv[1] + bias[1]);
      const float gg = tanhf_(s[2] + xv[2] + bias[2]);
      const float og = sigmoidf_(s[3] + xv[3] + bias[3]);
      const float cn = fg * creg + ig * gg;
      const float hn = og * tanhf_(cn);
      if (upd) { creg = cn; hreg = hn; }

      // pack 8 cols (8 threads) -> one dwordx4 store in lane tid%8==0
      unsigned int hb16 = (unsigned int)f_to_bf16bits(hreg);
      unsigned int a01 = (hb16 & 0xFFFFu) | (__shfl_xor(hb16, 1) << 16);
      unsigned int a23 = __shfl_xor(a01, 2);
      unsigned int a45 = __shfl_xor(a01, 4);
      unsigned int a67 = __shfl_xor(a23, 4);
      if ((tid & 7) == 0) {
        i32x4 v; v[0] = (int)a01; v[1] = (int)a23; v[2] = (int)a45; v[3] = (int)a67;
        store16_sys(hstore_base + (size_t)((t + 1) & 1) * (B_ * H_ * 2) + poff, v);
      }
      asm volatile("s_waitcnt vmcnt(0)" ::: "memory");  // this wave's stores at LLC
      if ((tid & 63) == 0)
        __hip_atomic_store(&flags[myflag_post], t + 1,
                           __ATOMIC_RELAXED, __HIP_MEMORY_SCOPE_AGENT);
    }
  }

  if (islast) {
    out[b * H_ + jglob] = hreg;
    out[B_ * H_ + b * H_ + jglob] = creg;
  } else {
    hstate[b * H_ + jglob] = hreg;
    cstate[b * H_ + jglob] = creg;
  }
}

// init: h0 -> hbuf[0] (bf16), zero flags (512 = 2*64*4). Re-runs every launch.
__global__ void init_k(const float* __restrict__ h0, __hip_bfloat16* __restrict__ hbuf,
                       int* __restrict__ flags) {
  int i = blockIdx.x * 256 + threadIdx.x;
  if (i < B_ * H_) hbuf[i] = __float2bfloat16(h0[i]);
  if (i < 2 * CG_ * 4) flags[i] = 0;
}

extern "C" void kernel_launch(void* const* d_in, const int* in_sizes, int n_in,
                              void* d_out, int out_size, void* d_ws, size_t ws_size,
                              hipStream_t stream) {
  const float* x       = (const float*)d_in[0];
  const int*   lengths = (const int*)d_in[1];
  const float* h0      = (const float*)d_in[2];
  const float* c0      = (const float*)d_in[3];
  const float* Wih     = (const float*)d_in[4];
  const float* Whh     = (const float*)d_in[5];
  const float* bih     = (const float*)d_in[6];
  const float* bhh     = (const float*)d_in[7];
  float* out = (float*)d_out;

  char* ws = (char*)d_ws;
  int* flags               = (int*)ws;                               // 8 KB region
  __hip_bfloat16* hbuf     = (__hip_bfloat16*)(ws + 8192);           // 2 x 64 KB
  float* hstate            = (float*)(ws + 8192 + 131072);           // 128 KB
  float* cstate            = (float*)(ws + 8192 + 262144);           // 128 KB
  __hip_bfloat16* xg       = (__hip_bfloat16*)(ws + 524288);

  size_t avail = (ws_size > 524288) ? ws_size - 524288 : 0;
  int tc = (int)(avail / ((size_t)B_ * G4_ * 2));
  if (tc > T_) tc = T_;
  tc &= ~3;               // M tile needs tc multiple of 4
  if (tc < 4) tc = 4;     // minimal chunk (assumes ws_size >= ~1.6 MB)

  hipLaunchKernelGGL(init_k, dim3(128), dim3(256), 0, stream, h0, hbuf, flags);
  for (int t0 = 0; t0 < T_; t0 += tc) {
    int len = min(tc, T_ - t0);
    dim3 gg(G4_ / 128, (len * B_) / 128);
    hipLaunchKernelGGL(xw_gemm, gg, dim3(256), 0, stream, x, Wih, xg, t0);
    hipLaunchKernelGGL(lstm_rec, dim3(NBLK), dim3(256), 0, stream,
                       xg, Whh, lengths, h0, c0, bih, bhh, hbuf, hstate, cstate,
                       flags, out, t0, t0 + len, (t0 == 0) ? 1 : 0,
                       (t0 + len >= T_) ? 1 : 0);
  }
}

// Round 14
// 8033.071 us; speedup vs baseline: 1.3135x; 1.3135x over previous
//
#include <hip/hip_runtime.h>
#include <hip/hip_bf16.h>

#define B_ 32
#define T_ 2048
#define D_ 512
#define H_ 1024
#define NBLK 128   // 2 batch-groups x 64 col-groups; 1 block/CU, co-resident
#define CG_ 64     // col groups
#define JPB 16     // h-columns per col-group (H_/CG_)
#define MROW 16    // batch rows per batch-group

typedef __attribute__((ext_vector_type(8))) short short8;
typedef __attribute__((ext_vector_type(4))) float f32x4;
typedef __attribute__((ext_vector_type(4))) int i32x4;

__device__ __forceinline__ float sigmoidf_(float x) { return 1.0f / (1.0f + __expf(-x)); }
__device__ __forceinline__ float tanhf_(float x) {
  float e = __expf(2.0f * x);
  return 1.0f - 2.0f / (e + 1.0f);
}
__device__ __forceinline__ unsigned short f_to_bf16bits(float f) {
  __hip_bfloat16 h = __float2bfloat16(f);
  return __builtin_bit_cast(unsigned short, h);
}

// 16B load bypassing L1/L2 (sc0 sc1): fresh from memory-side LLC, coalesces.
__device__ __forceinline__ i32x4 load16_sys(const void* p) {
  i32x4 v;
  asm volatile("global_load_dwordx4 %0, %1, off sc0 sc1" : "=v"(v) : "v"(p));
  return v;
}
// 4B LLC-fresh load (sc0 sc1), value ready on return (vmcnt inside). Coalesces.
__device__ __forceinline__ int load4_sys(const int* p) {
  int v;
  asm volatile("global_load_dword %0, %1, off sc0 sc1\n\t"
               "s_waitcnt vmcnt(0)"
               : "=v"(v) : "v"(p) : "memory");
  return v;
}
// 16B store written through to LLC (sc0 sc1); drained by explicit vmcnt(0).
__device__ __forceinline__ void store16_sys(void* p, i32x4 v) {
  asm volatile("global_store_dwordx4 %0, %1, off sc0 sc1" :: "v"(p), "v"(v) : "memory");
}

// ---------------------------------------------------------------------------
// FUSED persistent LSTM: 128 blocks x 256 thr (4 waves), batch-split.
// Block (bg = bid&1, cg = bid>>1): gates for batches [bg*16,+16) x h-cols
// [cg*16,+16) (=> 64 gate cols). Wave w owns K-slices: h-part K in
// [w*256,+256) of H=1024, x-part K in [w*128,+128) of D=512.
// Per step: x-part (load x fp32 -> bf16 frags -> 16 MFMAs) runs BEFORE the
// poll (independent of h, hides in the flag-wait bubble). Then R12's verified
// protocol verbatim: coalesced 16-flag poll -> sc0/sc1 h loads -> 32 MFMAs
// accumulate -> Gs -> barrier -> nonlin -> packed h store -> vmcnt drain ->
// barrier -> tid0 posts block flag. No xg buffer, no separate GEMM kernel,
// ONE launch for all 2048 steps (W_hh/W_ih fragments loaded once).
// Safety induction identical to R3/R6/R9/R12 (verified pre+post timing).
// ---------------------------------------------------------------------------
__global__ __launch_bounds__(256, 1) void lstm_rec(
    const float* __restrict__ x, const float* __restrict__ Wih,
    const float* __restrict__ Whh,
    const int* __restrict__ lengths, const float* __restrict__ h0,
    const float* __restrict__ c0, const float* __restrict__ bih,
    const float* __restrict__ bhh, __hip_bfloat16* hbuf,
    int* flags, float* __restrict__ out) {
  __shared__ float Gs[4][MROW][68];   // [k-slice][batch row][gate col]

  const int bid = blockIdx.x, tid = threadIdx.x;
  const int bg = bid & 1, cg = bid >> 1;
  const int lane = tid & 63, w = tid >> 6;
  const int lr = lane & 15, q = lane >> 4, kq = q * 8;
  const int kkb = w * 8;                 // h-part kk range [kkb,kkb+8)

  // --- W_hh fragments (stationary): gate col ni*16+lr local ---
  short8 wf[4][8];
#pragma unroll
  for (int ni = 0; ni < 4; ++ni) {
    const int gcol = ni * H_ + cg * JPB + lr;
    const float* wbase = Whh + (size_t)gcol * H_ + kq;
#pragma unroll
    for (int kk2 = 0; kk2 < 8; ++kk2) {
      const int k0 = (kkb + kk2) * 32;
      f32x4 w0 = *(const f32x4*)(wbase + k0);
      f32x4 w1 = *(const f32x4*)(wbase + k0 + 4);
      __hip_bfloat16 tw_[8];
#pragma unroll
      for (int e = 0; e < 4; ++e) { tw_[e] = __float2bfloat16(w0[e]); tw_[4 + e] = __float2bfloat16(w1[e]); }
      wf[ni][kk2] = *(const short8*)&tw_[0];
    }
  }
  // --- W_ih fragments (stationary): x-part K-slice [w*128,+128) of D ---
  short8 wfx[4][4];
#pragma unroll
  for (int ni = 0; ni < 4; ++ni) {
    const int gcol = ni * H_ + cg * JPB + lr;
    const float* wbase = Wih + (size_t)gcol * D_ + w * 128 + kq;
#pragma unroll
    for (int kkx = 0; kkx < 4; ++kkx) {
      f32x4 w0 = *(const f32x4*)(wbase + kkx * 32);
      f32x4 w1 = *(const f32x4*)(wbase + kkx * 32 + 4);
      __hip_bfloat16 tw_[8];
#pragma unroll
      for (int e = 0; e < 4; ++e) { tw_[e] = __float2bfloat16(w0[e]); tw_[4 + e] = __float2bfloat16(w1[e]); }
      wfx[ni][kkx] = *(const short8*)&tw_[0];
    }
  }

  // nonlinearity ownership: ALL 256 threads, each owns (batch row bloc, col j1)
  const int bloc = tid >> 4, j1 = tid & 15;
  const int b = bg * MROW + bloc;
  const int jglob = cg * JPB + j1;
  const int len_b = lengths[b];
  int maxlen = 0;
  for (int p = 0; p < B_; ++p) maxlen = max(maxlen, lengths[p]);
  const int tend = maxlen;

  float hreg = h0[b * H_ + jglob], creg = c0[b * H_ + jglob];
  float bias[4];
#pragma unroll
  for (int p = 0; p < 4; ++p) bias[p] = bih[p * H_ + jglob] + bhh[p * H_ + jglob];

  // wave w's producers: blocks (bg, cgp), cgp in [w*16, w*16+16)
  const int* myflag = &flags[bg * CG_ + w * 16 + lr];
  // producer store: lanes tid%8==0 store 16B; 2 stores per batch row
  char* const hstore_base = (char*)hbuf;
  const size_t poff = (size_t)b * (H_ * 2) + cg * (JPB * 2) + ((tid >> 3) & 1) * 16;
  // x row for this lane's MFMA A-fragment (row = bg*16+lr), k base w*128+kq
  const float* xrow = x + (size_t)(bg * MROW + lr) * T_ * D_ + w * 128 + kq;

  for (int t = 0; t < tend; ++t) {
    // ---- x-part: load x (cacheable, L2/L3), convert, 16 MFMAs ----
    // Independent of h -> fills the poll-wait bubble.
    f32x4 acc[4];
#pragma unroll
    for (int ni = 0; ni < 4; ++ni) acc[ni] = (f32x4){0.f, 0.f, 0.f, 0.f};
    {
      const float* xt = xrow + (size_t)t * D_;
      short8 afx[4];
#pragma unroll
      for (int kkx = 0; kkx < 4; ++kkx) {
        f32x4 a0 = *(const f32x4*)(xt + kkx * 32);
        f32x4 a1 = *(const f32x4*)(xt + kkx * 32 + 4);
        __hip_bfloat16 ta_[8];
#pragma unroll
        for (int e = 0; e < 4; ++e) { ta_[e] = __float2bfloat16(a0[e]); ta_[4 + e] = __float2bfloat16(a1[e]); }
        afx[kkx] = *(const short8*)&ta_[0];
      }
#pragma unroll
      for (int kkx = 0; kkx < 4; ++kkx)
#pragma unroll
        for (int ni = 0; ni < 4; ++ni)
          acc[ni] = __builtin_amdgcn_mfma_f32_16x16x32_bf16(afx[kkx], wfx[ni][kkx], acc[ni], 0, 0, 0);
    }

    // ---- per-wave poll: ONE coalesced line read of 16 producer flags ----
    while (true) {
      int f = load4_sys(myflag);
      if (__all((lane >= 16) || (f >= t))) break;
      __builtin_amdgcn_s_sleep(1);
    }

    // ---- A-fragments: coalescing 16B L2-bypass loads (16 rows only) ----
    const char* hb = (const char*)(hbuf + (size_t)(t & 1) * (B_ * H_));
    const char* rowp = hb + (size_t)(bg * MROW + lr) * (H_ * 2) + kkb * 64 + q * 16;
    i32x4 raw[8];
#pragma unroll
    for (int kk2 = 0; kk2 < 8; ++kk2)
      raw[kk2] = load16_sys(rowp + kk2 * 64);
    asm volatile("s_waitcnt vmcnt(0)" ::: "memory");
    __builtin_amdgcn_sched_barrier(0);

    short8 af[8];
#pragma unroll
    for (int kk2 = 0; kk2 < 8; ++kk2) {
      union { i32x4 i; short8 s; } cv;
      cv.i = raw[kk2];
      af[kk2] = cv.s;
    }

    // ---- h-part MFMAs accumulate on top of the x-part ----
#pragma unroll
    for (int kk2 = 0; kk2 < 8; ++kk2)
#pragma unroll
      for (int ni = 0; ni < 4; ++ni)
        acc[ni] = __builtin_amdgcn_mfma_f32_16x16x32_bf16(af[kk2], wf[ni][kk2], acc[ni], 0, 0, 0);

    // ---- write partials ----
#pragma unroll
    for (int ni = 0; ni < 4; ++ni)
#pragma unroll
      for (int rr = 0; rr < 4; ++rr)
        Gs[w][q * 4 + rr][ni * 16 + lr] = acc[ni][rr];
    __syncthreads();

    // ---- nonlinearity: thread owns (b, jglob); 16 LDS reads ----
    {
      const int upd = (t < len_b);
      float s[4];
#pragma unroll
      for (int p = 0; p < 4; ++p) {
        const int cb = p * 16 + j1;
        s[p] = (Gs[0][bloc][cb] + Gs[1][bloc][cb]) + (Gs[2][bloc][cb] + Gs[3][bloc][cb]);
      }
      const float ig = sigmoidf_(s[0] + bias[0]);
      const float fg = sigmoidf_(s[1] + bias[1]);
      const float gg = tanhf_(s[2] + bias[2]);
      const float og = sigmoidf_(s[3] + bias[3]);
      const float cn = fg * creg + ig * gg;
      const float hn = og * tanhf_(cn);
      if (upd) { creg = cn; hreg = hn; }

      // pack 8 cols (8 threads) -> one dwordx4 store in lane tid%8==0
      unsigned int hb16 = (unsigned int)f_to_bf16bits(hreg);
      unsigned int a01 = (hb16 & 0xFFFFu) | (__shfl_xor(hb16, 1) << 16);
      unsigned int a23 = __shfl_xor(a01, 2);
      unsigned int a45 = __shfl_xor(a01, 4);
      unsigned int a67 = __shfl_xor(a23, 4);
      if ((tid & 7) == 0) {
        i32x4 v; v[0] = (int)a01; v[1] = (int)a23; v[2] = (int)a45; v[3] = (int)a67;
        store16_sys(hstore_base + (size_t)((t + 1) & 1) * (B_ * H_ * 2) + poff, v);
      }
      asm volatile("s_waitcnt vmcnt(0)" ::: "memory");
    }
    __syncthreads();   // all stores drained (explicit vmcnt above) before flag
    if (tid == 0)
      __hip_atomic_store(&flags[bg * CG_ + cg], t + 1, __ATOMIC_RELAXED, __HIP_MEMORY_SCOPE_AGENT);
  }

  out[b * H_ + jglob] = hreg;
  out[B_ * H_ + b * H_ + jglob] = creg;
}

// init: h0 -> hbuf[0] (bf16), zero flags. Re-runs every launch (graph replay safe).
__global__ void init_k(const float* __restrict__ h0, __hip_bfloat16* __restrict__ hbuf,
                       int* __restrict__ flags) {
  int i = blockIdx.x * 256 + threadIdx.x;
  if (i < B_ * H_) hbuf[i] = __float2bfloat16(h0[i]);
  if (i < NBLK) flags[i] = 0;
}

extern "C" void kernel_launch(void* const* d_in, const int* in_sizes, int n_in,
                              void* d_out, int out_size, void* d_ws, size_t ws_size,
                              hipStream_t stream) {
  const float* x       = (const float*)d_in[0];
  const int*   lengths = (const int*)d_in[1];
  const float* h0      = (const float*)d_in[2];
  const float* c0      = (const float*)d_in[3];
  const float* Wih     = (const float*)d_in[4];
  const float* Whh     = (const float*)d_in[5];
  const float* bih     = (const float*)d_in[6];
  const float* bhh     = (const float*)d_in[7];
  float* out = (float*)d_out;

  char* ws = (char*)d_ws;
  int* flags               = (int*)ws;                               // 8 KB region
  __hip_bfloat16* hbuf     = (__hip_bfloat16*)(ws + 8192);           // 2 x 64 KB

  hipLaunchKernelGGL(init_k, dim3(128), dim3(256), 0, stream, h0, hbuf, flags);
  hipLaunchKernelGGL(lstm_rec, dim3(NBLK), dim3(256), 0, stream,
                     x, Wih, Whh, lengths, h0, c0, bih, bhh, hbuf, flags, out);
}

// Round 15
// 7962.710 us; speedup vs baseline: 1.3251x; 1.0088x over previous
//
#include <hip/hip_runtime.h>
#include <hip/hip_bf16.h>

#define B_ 32
#define T_ 2048
#define D_ 512
#define H_ 1024
#define NBLK 128   // 2 batch-groups x 64 col-groups; 1 block/CU, co-resident
#define CG_ 64     // col groups
#define JPB 16     // h-columns per col-group (H_/CG_)
#define MROW 16    // batch rows per batch-group

typedef __attribute__((ext_vector_type(8))) short short8;
typedef __attribute__((ext_vector_type(4))) float f32x4;
typedef __attribute__((ext_vector_type(4))) int i32x4;

__device__ __forceinline__ float sigmoidf_(float x) { return 1.0f / (1.0f + __expf(-x)); }
__device__ __forceinline__ float tanhf_(float x) {
  float e = __expf(2.0f * x);
  return 1.0f - 2.0f / (e + 1.0f);
}
__device__ __forceinline__ unsigned short f_to_bf16bits(float f) {
  __hip_bfloat16 h = __float2bfloat16(f);
  return __builtin_bit_cast(unsigned short, h);
}

// 16B load bypassing L1/L2 (sc0 sc1): fresh from memory-side LLC, coalesces.
__device__ __forceinline__ i32x4 load16_sys(const void* p) {
  i32x4 v;
  asm volatile("global_load_dwordx4 %0, %1, off sc0 sc1" : "=v"(v) : "v"(p));
  return v;
}
// 4B LLC-fresh load (sc0 sc1), value ready on return (vmcnt inside). Coalesces.
__device__ __forceinline__ int load4_sys(const int* p) {
  int v;
  asm volatile("global_load_dword %0, %1, off sc0 sc1\n\t"
               "s_waitcnt vmcnt(0)"
               : "=v"(v) : "v"(p) : "memory");
  return v;
}
// 16B store written through to LLC (sc0 sc1); drained by explicit vmcnt(0).
__device__ __forceinline__ void store16_sys(void* p, i32x4 v) {
  asm volatile("global_store_dwordx4 %0, %1, off sc0 sc1" :: "v"(p), "v"(v) : "memory");
}

// ---------------------------------------------------------------------------
// FUSED persistent LSTM (R14 data path) with SINGLE barrier per step:
//  - Gs parity-double-buffered (structure verified correct in R13 pre+post).
//  - After the barrier: nonlin -> packed h store -> per-wave vmcnt(0) drain ->
//    wave leader ds_add on LDS counter cnt[t&1]; the 4th arriver resets the
//    counter and posts the R12-style block flag. Flag fires at max(waves)
//    with no barrier-release latency; other waves run ahead into step t+1's
//    x-part and poll.
// Safety induction (same certificates as R9/R12/R13, re-derived):
//  * flag=t+1 posted only after all 4 waves' h_{t+1} stores drained (each
//    ds_add follows its wave's vmcnt(0); 4th arriver => all drained).
//  * h stores happen post-barrier, i.e. after ALL 4 waves' polls(t) saw
//    their 16 producers >= t; union of the 4 poll sets = all 64 same-bg
//    blocks = exactly the consumers of this block's h cols => every step
//    t-1 read of hbuf[(t+1)&1] completed before the overwrite.
//  * Gs[p] reads at step t precede that wave's barrier(t+1) arrival; Gs[p]
//    writes at step t+2 follow barrier(t+2) > barrier(t+1) join => no race.
//  * cnt[t&1] reset by the last step-t arriver precedes its barrier(t+1)
//    arrival; any step-t+2 ds_add follows that wave's barrier(t+2) pass.
// Deadlock-free: flags monotone; every wave always reaches its ds_add.
// ---------------------------------------------------------------------------
__global__ __launch_bounds__(256, 1) void lstm_rec(
    const float* __restrict__ x, const float* __restrict__ Wih,
    const float* __restrict__ Whh,
    const int* __restrict__ lengths, const float* __restrict__ h0,
    const float* __restrict__ c0, const float* __restrict__ bih,
    const float* __restrict__ bhh, __hip_bfloat16* hbuf,
    int* flags, float* __restrict__ out) {
  __shared__ float Gs[2][4][MROW][68];   // [parity][k-slice][batch row][gate col]
  __shared__ int cnt[2];                 // per-parity completion counters

  const int bid = blockIdx.x, tid = threadIdx.x;
  const int bg = bid & 1, cg = bid >> 1;
  const int lane = tid & 63, w = tid >> 6;
  const int lr = lane & 15, q = lane >> 4, kq = q * 8;
  const int kkb = w * 8;                 // h-part kk range [kkb,kkb+8)

  // --- W_hh fragments (stationary): gate col ni*16+lr local ---
  short8 wf[4][8];
#pragma unroll
  for (int ni = 0; ni < 4; ++ni) {
    const int gcol = ni * H_ + cg * JPB + lr;
    const float* wbase = Whh + (size_t)gcol * H_ + kq;
#pragma unroll
    for (int kk2 = 0; kk2 < 8; ++kk2) {
      const int k0 = (kkb + kk2) * 32;
      f32x4 w0 = *(const f32x4*)(wbase + k0);
      f32x4 w1 = *(const f32x4*)(wbase + k0 + 4);
      __hip_bfloat16 tw_[8];
#pragma unroll
      for (int e = 0; e < 4; ++e) { tw_[e] = __float2bfloat16(w0[e]); tw_[4 + e] = __float2bfloat16(w1[e]); }
      wf[ni][kk2] = *(const short8*)&tw_[0];
    }
  }
  // --- W_ih fragments (stationary): x-part K-slice [w*128,+128) of D ---
  short8 wfx[4][4];
#pragma unroll
  for (int ni = 0; ni < 4; ++ni) {
    const int gcol = ni * H_ + cg * JPB + lr;
    const float* wbase = Wih + (size_t)gcol * D_ + w * 128 + kq;
#pragma unroll
    for (int kkx = 0; kkx < 4; ++kkx) {
      f32x4 w0 = *(const f32x4*)(wbase + kkx * 32);
      f32x4 w1 = *(const f32x4*)(wbase + kkx * 32 + 4);
      __hip_bfloat16 tw_[8];
#pragma unroll
      for (int e = 0; e < 4; ++e) { tw_[e] = __float2bfloat16(w0[e]); tw_[4 + e] = __float2bfloat16(w1[e]); }
      wfx[ni][kkx] = *(const short8*)&tw_[0];
    }
  }

  if (tid < 2) cnt[tid] = 0;   // visible to all by the step-0 barrier

  // nonlinearity ownership: ALL 256 threads, each owns (batch row bloc, col j1)
  const int bloc = tid >> 4, j1 = tid & 15;
  const int b = bg * MROW + bloc;
  const int jglob = cg * JPB + j1;
  const int len_b = lengths[b];
  int maxlen = 0;
  for (int p = 0; p < B_; ++p) maxlen = max(maxlen, lengths[p]);
  const int tend = maxlen;

  float hreg = h0[b * H_ + jglob], creg = c0[b * H_ + jglob];
  float bias[4];
#pragma unroll
  for (int p = 0; p < 4; ++p) bias[p] = bih[p * H_ + jglob] + bhh[p * H_ + jglob];

  // wave w's producers: blocks (bg, cgp), cgp in [w*16, w*16+16)
  const int* myflag = &flags[bg * CG_ + w * 16 + lr];
  // producer store: lanes tid%8==0 store 16B; 2 stores per batch row
  char* const hstore_base = (char*)hbuf;
  const size_t poff = (size_t)b * (H_ * 2) + cg * (JPB * 2) + ((tid >> 3) & 1) * 16;
  // x row for this lane's MFMA A-fragment (row = bg*16+lr), k base w*128+kq
  const float* xrow = x + (size_t)(bg * MROW + lr) * T_ * D_ + w * 128 + kq;

  for (int t = 0; t < tend; ++t) {
    // ---- x-part: load x (cacheable, L2/L3), convert, 16 MFMAs ----
    // Independent of h -> fills the poll-wait bubble / previous step's tail.
    f32x4 acc[4];
#pragma unroll
    for (int ni = 0; ni < 4; ++ni) acc[ni] = (f32x4){0.f, 0.f, 0.f, 0.f};
    {
      const float* xt = xrow + (size_t)t * D_;
      short8 afx[4];
#pragma unroll
      for (int kkx = 0; kkx < 4; ++kkx) {
        f32x4 a0 = *(const f32x4*)(xt + kkx * 32);
        f32x4 a1 = *(const f32x4*)(xt + kkx * 32 + 4);
        __hip_bfloat16 ta_[8];
#pragma unroll
        for (int e = 0; e < 4; ++e) { ta_[e] = __float2bfloat16(a0[e]); ta_[4 + e] = __float2bfloat16(a1[e]); }
        afx[kkx] = *(const short8*)&ta_[0];
      }
#pragma unroll
      for (int kkx = 0; kkx < 4; ++kkx)
#pragma unroll
        for (int ni = 0; ni < 4; ++ni)
          acc[ni] = __builtin_amdgcn_mfma_f32_16x16x32_bf16(afx[kkx], wfx[ni][kkx], acc[ni], 0, 0, 0);
    }

    // ---- per-wave poll: ONE coalesced line read of 16 producer flags ----
    while (true) {
      int f = load4_sys(myflag);
      if (__all((lane >= 16) || (f >= t))) break;
      __builtin_amdgcn_s_sleep(1);
    }

    // ---- A-fragments: coalescing 16B L2-bypass loads (16 rows only) ----
    const char* hb = (const char*)(hbuf + (size_t)(t & 1) * (B_ * H_));
    const char* rowp = hb + (size_t)(bg * MROW + lr) * (H_ * 2) + kkb * 64 + q * 16;
    i32x4 raw[8];
#pragma unroll
    for (int kk2 = 0; kk2 < 8; ++kk2)
      raw[kk2] = load16_sys(rowp + kk2 * 64);
    asm volatile("s_waitcnt vmcnt(0)" ::: "memory");
    __builtin_amdgcn_sched_barrier(0);

    short8 af[8];
#pragma unroll
    for (int kk2 = 0; kk2 < 8; ++kk2) {
      union { i32x4 i; short8 s; } cv;
      cv.i = raw[kk2];
      af[kk2] = cv.s;
    }

    // ---- h-part MFMAs accumulate on top of the x-part ----
#pragma unroll
    for (int kk2 = 0; kk2 < 8; ++kk2)
#pragma unroll
      for (int ni = 0; ni < 4; ++ni)
        acc[ni] = __builtin_amdgcn_mfma_f32_16x16x32_bf16(af[kk2], wf[ni][kk2], acc[ni], 0, 0, 0);

    // ---- write partials to this parity's Gs ----
#pragma unroll
    for (int ni = 0; ni < 4; ++ni)
#pragma unroll
      for (int rr = 0; rr < 4; ++rr)
        Gs[t & 1][w][q * 4 + rr][ni * 16 + lr] = acc[ni][rr];
    __syncthreads();   // the ONLY barrier: joins all 4 waves' polls+reads+MFMA

    // ---- nonlinearity + per-wave-drained h store + counter-gated flag ----
    {
      const int upd = (t < len_b);
      const float (*G)[MROW][68] = Gs[t & 1];
      float s[4];
#pragma unroll
      for (int p = 0; p < 4; ++p) {
        const int cb = p * 16 + j1;
        s[p] = (G[0][bloc][cb] + G[1][bloc][cb]) + (G[2][bloc][cb] + G[3][bloc][cb]);
      }
      const float ig = sigmoidf_(s[0] + bias[0]);
      const float fg = sigmoidf_(s[1] + bias[1]);
      const float gg = tanhf_(s[2] + bias[2]);
      const float og = sigmoidf_(s[3] + bias[3]);
      const float cn = fg * creg + ig * gg;
      const float hn = og * tanhf_(cn);
      if (upd) { creg = cn; hreg = hn; }

      // pack 8 cols (8 threads) -> one dwordx4 store in lane tid%8==0
      unsigned int hb16 = (unsigned int)f_to_bf16bits(hreg);
      unsigned int a01 = (hb16 & 0xFFFFu) | (__shfl_xor(hb16, 1) << 16);
      unsigned int a23 = __shfl_xor(a01, 2);
      unsigned int a45 = __shfl_xor(a01, 4);
      unsigned int a67 = __shfl_xor(a23, 4);
      if ((tid & 7) == 0) {
        i32x4 v; v[0] = (int)a01; v[1] = (int)a23; v[2] = (int)a45; v[3] = (int)a67;
        store16_sys(hstore_base + (size_t)((t + 1) & 1) * (B_ * H_ * 2) + poff, v);
      }
      asm volatile("s_waitcnt vmcnt(0)" ::: "memory");  // this wave's stores at LLC
      __builtin_amdgcn_sched_barrier(0);
      if (lane == 0) {
        int r = atomicAdd(&cnt[t & 1], 1);             // ds_add_rtn (LDS)
        if (r == 3) {                                   // 4th wave: all drained
          cnt[t & 1] = 0;                               // reset for step t+2
          __hip_atomic_store(&flags[bg * CG_ + cg], t + 1,
                             __ATOMIC_RELAXED, __HIP_MEMORY_SCOPE_AGENT);
        }
      }
    }
  }

  out[b * H_ + jglob] = hreg;
  out[B_ * H_ + b * H_ + jglob] = creg;
}

// init: h0 -> hbuf[0] (bf16), zero flags. Re-runs every launch (graph replay safe).
__global__ void init_k(const float* __restrict__ h0, __hip_bfloat16* __restrict__ hbuf,
                       int* __restrict__ flags) {
  int i = blockIdx.x * 256 + threadIdx.x;
  if (i < B_ * H_) hbuf[i] = __float2bfloat16(h0[i]);
  if (i < NBLK) flags[i] = 0;
}

extern "C" void kernel_launch(void* const* d_in, const int* in_sizes, int n_in,
                              void* d_out, int out_size, void* d_ws, size_t ws_size,
                              hipStream_t stream) {
  const float* x       = (const float*)d_in[0];
  const int*   lengths = (const int*)d_in[1];
  const float* h0      = (const float*)d_in[2];
  const float* c0      = (const float*)d_in[3];
  const float* Wih     = (const float*)d_in[4];
  const float* Whh     = (const float*)d_in[5];
  const float* bih     = (const float*)d_in[6];
  const float* bhh     = (const float*)d_in[7];
  float* out = (float*)d_out;

  char* ws = (char*)d_ws;
  int* flags               = (int*)ws;                               // 8 KB region
  __hip_bfloat16* hbuf     = (__hip_bfloat16*)(ws + 8192);           // 2 x 64 KB

  hipLaunchKernelGGL(init_k, dim3(128), dim3(256), 0, stream, h0, hbuf, flags);
  hipLaunchKernelGGL(lstm_rec, dim3(NBLK), dim3(256), 0, stream,
                     x, Wih, Whh, lengths, h0, c0, bih, bhh, hbuf, flags, out);
}